// Round 4
// baseline (263.180 us; speedup 1.0000x reference)
//
#include <hip/hip_runtime.h>

#define F_EDGE 8
#define H 8

__device__ __forceinline__ unsigned short f2bf(float f) {
    unsigned u = __float_as_uint(f);
    unsigned r = u + 0x7fffu + ((u >> 16) & 1u);
    return (unsigned short)(r >> 16);
}
__device__ __forceinline__ float bflo(unsigned u) { return __uint_as_float(u << 16); }
__device__ __forceinline__ float bfhi(unsigned u) { return __uint_as_float(u & 0xffff0000u); }

// out[g] = blast (pool accumulates on top)
__global__ void init_out_kernel(float* __restrict__ out,
                                const float* __restrict__ blast, int n) {
    int g = blockIdx.x * blockDim.x + threadIdx.x;
    if (g < n) out[g] = blast[0];
}

__global__ void zero_int_kernel(int* __restrict__ p, int n) {
    int i = blockIdx.x * blockDim.x + threadIdx.x;
    if (i < n) p[i] = 0;
}

// ---- CSR build (graph identical for both layers; built once) ----
__global__ __launch_bounds__(256) void hist_kernel(const int* __restrict__ ei,
                                                   int* __restrict__ cnt, int E) {
    int e = blockIdx.x * blockDim.x + threadIdx.x;
    if (e < E) atomicAdd(&cnt[ei[E + e]], 1);
}

// per-block inclusive scan -> exclusive-within-block + block total
__global__ __launch_bounds__(256) void scan1_kernel(const int* __restrict__ cnt,
                                                    int* __restrict__ excl,
                                                    int* __restrict__ bsum, int n) {
    __shared__ int s[256];
    int tid = threadIdx.x;
    int gid = blockIdx.x * 256 + tid;
    int v = (gid < n) ? cnt[gid] : 0;
    s[tid] = v;
    __syncthreads();
#pragma unroll
    for (int off = 1; off < 256; off <<= 1) {
        int t = (tid >= off) ? s[tid - off] : 0;
        __syncthreads();
        s[tid] += t;
        __syncthreads();
    }
    if (gid < n) excl[gid] = s[tid] - v;
    if (tid == 255) bsum[blockIdx.x] = s[255];
}

// single-block exclusive scan of block sums (nb <= 256 for this problem size)
__global__ __launch_bounds__(256) void scan2_kernel(const int* __restrict__ bsum,
                                                    int* __restrict__ bsumx, int nb) {
    __shared__ int s[256];
    int tid = threadIdx.x;
    int v = (tid < nb) ? bsum[tid] : 0;
    s[tid] = v;
    __syncthreads();
#pragma unroll
    for (int off = 1; off < 256; off <<= 1) {
        int t = (tid >= off) ? s[tid - off] : 0;
        __syncthreads();
        s[tid] += t;
        __syncthreads();
    }
    if (tid < nb) bsumx[tid] = s[tid] - v;
}

__global__ __launch_bounds__(256) void scan3_kernel(const int* __restrict__ excl,
                                                    const int* __restrict__ bsumx,
                                                    int* __restrict__ row_start,
                                                    int* __restrict__ cursor, int n) {
    int i = blockIdx.x * 256 + threadIdx.x;
    if (i < n) {
        int v = excl[i] + bsumx[blockIdx.x];
        row_start[i] = v;
        cursor[i] = v;
    }
}

// scatter edges into dst-sorted order; also permute ea so agg reads it coalesced
__global__ __launch_bounds__(256) void scatter_kernel(
    const int* __restrict__ ei, const float* __restrict__ ea,
    int* __restrict__ cursor, int* __restrict__ src_s,
    float* __restrict__ ea_s, int E) {
    int e = blockIdx.x * blockDim.x + threadIdx.x;
    if (e >= E) return;
    int src = ei[e];
    int dst = ei[E + e];
    int pos = atomicAdd(&cursor[dst], 1);
    src_s[pos] = src;
    const float4* av = (const float4*)(ea + (size_t)e * F_EDGE);
    float4* ov = (float4*)(ea_s + (size_t)pos * F_EDGE);
    ov[0] = av[0];
    ov[1] = av[1];
}

// ---- Per-node factorized precompute (unchanged structure from R3) ----
//   Pt[n][j][k]   = sum_i feat[n][i] * We[k][i*H+j]   (bf16)
//   q[n][j]       = sum_i feat[n][i] * be[i*H+j]
//   seed[n][j]    = b[j] + sum_i feat[n][i] * root[i*H+j]
template <int IN, bool RELU>
__global__ __launch_bounds__(256) void prep_kernel(
    const float* __restrict__ feat, const float* __restrict__ We,
    const float* __restrict__ be, const float* __restrict__ root,
    const float* __restrict__ b, unsigned short* __restrict__ Pt,
    float* __restrict__ q, float* __restrict__ seed, int n_nodes) {
    __shared__ float sW[IN * H * 12];
    int tid = threadIdx.x;
    for (int t = tid; t < IN * H * 12; t += 256) {
        int r = t / 12, m = t - r * 12;  // r = i*H + j
        float v = 0.f;
        if (m < 8) v = We[m * (IN * H) + r];
        else if (m == 8) v = be[r];
        else if (m == 9) v = root[r];
        sW[t] = v;
    }
    __syncthreads();

    int n = blockIdx.x * 32 + (tid >> 3);
    if (n >= n_nodes) return;
    int j = tid & 7;

    float f[IN];
    const float4* fv = (const float4*)(feat + (long long)n * IN);
#pragma unroll
    for (int i4 = 0; i4 < IN / 4; ++i4) {
        float4 v = fv[i4];
        f[i4 * 4 + 0] = v.x; f[i4 * 4 + 1] = v.y;
        f[i4 * 4 + 2] = v.z; f[i4 * 4 + 3] = v.w;
    }
    if (RELU) {
#pragma unroll
        for (int i = 0; i < IN; ++i) f[i] = f[i] > 0.f ? f[i] : 0.f;
    }

    float p[8] = {0.f, 0.f, 0.f, 0.f, 0.f, 0.f, 0.f, 0.f};
    float qq = 0.f, hr = 0.f;
#pragma unroll
    for (int i = 0; i < IN; ++i) {
        const float* row = &sW[(i * 8 + j) * 12];
        float4 w0 = *(const float4*)row;
        float4 w1 = *(const float4*)(row + 4);
        float2 br = *(const float2*)(row + 8);
        float fi = f[i];
        p[0] = fmaf(fi, w0.x, p[0]); p[1] = fmaf(fi, w0.y, p[1]);
        p[2] = fmaf(fi, w0.z, p[2]); p[3] = fmaf(fi, w0.w, p[3]);
        p[4] = fmaf(fi, w1.x, p[4]); p[5] = fmaf(fi, w1.y, p[5]);
        p[6] = fmaf(fi, w1.z, p[6]); p[7] = fmaf(fi, w1.w, p[7]);
        qq = fmaf(fi, br.x, qq);
        hr = fmaf(fi, br.y, hr);
    }
    uint4 pw;
    pw.x = (unsigned)f2bf(p[0]) | ((unsigned)f2bf(p[1]) << 16);
    pw.y = (unsigned)f2bf(p[2]) | ((unsigned)f2bf(p[3]) << 16);
    pw.z = (unsigned)f2bf(p[4]) | ((unsigned)f2bf(p[5]) << 16);
    pw.w = (unsigned)f2bf(p[6]) | ((unsigned)f2bf(p[7]) << 16);
    *(uint4*)(Pt + ((long long)n * H + j) * F_EDGE) = pw;
    q[(long long)n * H + j] = qq;
    seed[(long long)n * H + j] = hr + b[j];
}

// ---- Atomic-free CSR aggregation: one wave per node ----
// lane = (ee, j): edge-octet ee = lane>>3, feature j = lane&7.
// per chunk of 8 edges: msg_j(e) = q[src][j] + sum_k ea_s[e][k]*Pt[src][j][k]
// shfl-reduce over ee, then feat_out[n][j] = seed[n][j] + total  (in place).
__global__ __launch_bounds__(256) void agg_csr_kernel(
    const int* __restrict__ row_start, const int* __restrict__ cnt,
    const int* __restrict__ src_s, const float* __restrict__ ea_s,
    const unsigned short* __restrict__ Pt, const float* __restrict__ q,
    float* __restrict__ feat_io,  // seed in, aggregated out (same array)
    int n_nodes) {
    int wave = threadIdx.x >> 6;
    int lane = threadIdx.x & 63;
    int n = blockIdx.x * 4 + wave;
    if (n >= n_nodes) return;
    int ee = lane >> 3, j = lane & 7;

    int start = row_start[n];
    int end = start + cnt[n];
    float acc = 0.f;
    for (int base = start; base < end; base += 8) {
        int idx = base + ee;
        if (idx < end) {
            int src = src_s[idx];
            const float4* av = (const float4*)(ea_s + (size_t)idx * F_EDGE);
            float4 a0 = av[0], a1 = av[1];
            uint4 pw = *(const uint4*)(Pt + ((size_t)src * H + j) * F_EDGE);
            float m = q[(size_t)src * H + j];
            m = fmaf(a0.x, bflo(pw.x), m);
            m = fmaf(a0.y, bfhi(pw.x), m);
            m = fmaf(a0.z, bflo(pw.y), m);
            m = fmaf(a0.w, bfhi(pw.y), m);
            m = fmaf(a1.x, bflo(pw.z), m);
            m = fmaf(a1.y, bfhi(pw.z), m);
            m = fmaf(a1.z, bflo(pw.w), m);
            m = fmaf(a1.w, bfhi(pw.w), m);
            acc += m;
        }
    }
    acc += __shfl_xor(acc, 8, 64);
    acc += __shfl_xor(acc, 16, 64);
    acc += __shfl_xor(acc, 32, 64);
    if (ee == 0) {
        size_t o = (size_t)n * H + j;
        feat_io[o] = feat_io[o] + acc;
    }
}

// Pool: per-block LDS bins (batch sorted -> few hot bins), one atomic/bin
__global__ __launch_bounds__(256) void pool_kernel(
    const float* __restrict__ h2pre, const int* __restrict__ batch,
    const float* __restrict__ Wlast, float* __restrict__ out,
    int n_nodes, int n_graphs) {
    __shared__ float bins[512];
    bool use_bins = (n_graphs <= 512);
    if (use_bins) {
        for (int t = threadIdx.x; t < n_graphs; t += 256) bins[t] = 0.f;
        __syncthreads();
    }
    float wl[8];
#pragma unroll
    for (int j = 0; j < 8; ++j) wl[j] = Wlast[j];

    int base = blockIdx.x * 1024;
#pragma unroll
    for (int r = 0; r < 4; ++r) {
        int n = base + r * 256 + threadIdx.x;
        if (n < n_nodes) {
            const float4* hv = (const float4*)(h2pre + (long long)n * H);
            float4 h0 = hv[0], h1 = hv[1];
            float c = 0.f;
            c = fmaf(fmaxf(h0.x, 0.f), wl[0], c);
            c = fmaf(fmaxf(h0.y, 0.f), wl[1], c);
            c = fmaf(fmaxf(h0.z, 0.f), wl[2], c);
            c = fmaf(fmaxf(h0.w, 0.f), wl[3], c);
            c = fmaf(fmaxf(h1.x, 0.f), wl[4], c);
            c = fmaf(fmaxf(h1.y, 0.f), wl[5], c);
            c = fmaf(fmaxf(h1.z, 0.f), wl[6], c);
            c = fmaf(fmaxf(h1.w, 0.f), wl[7], c);
            if (use_bins) atomicAdd(&bins[batch[n]], c);
            else unsafeAtomicAdd(&out[batch[n]], c);
        }
    }
    if (use_bins) {
        __syncthreads();
        for (int t = threadIdx.x; t < n_graphs; t += 256) {
            float v = bins[t];
            if (v != 0.f) unsafeAtomicAdd(&out[t], v);
        }
    }
}

extern "C" void kernel_launch(void* const* d_in, const int* in_sizes, int n_in,
                              void* d_out, int out_size, void* d_ws, size_t ws_size,
                              hipStream_t stream) {
    const float* x     = (const float*)d_in[0];
    const int*   ei    = (const int*)d_in[1];
    const float* ea    = (const float*)d_in[2];
    const int*   batch = (const int*)d_in[3];
    const float* We1   = (const float*)d_in[4];
    const float* be1   = (const float*)d_in[5];
    const float* root1 = (const float*)d_in[6];
    const float* b1    = (const float*)d_in[7];
    const float* We2   = (const float*)d_in[8];
    const float* be2   = (const float*)d_in[9];
    const float* root2 = (const float*)d_in[10];
    const float* b2    = (const float*)d_in[11];
    const float* Wlast = (const float*)d_in[12];
    const float* blast = (const float*)d_in[13];
    float* out = (float*)d_out;

    int n_nodes = in_sizes[0] / 16;
    int E = in_sizes[1] / 2;
    int nb = (n_nodes + 255) / 256;  // <= 256 for this problem size

    // ---- workspace carve (16B-aligned chunks) ----
    char* w = (char*)d_ws;
    auto carve = [&](size_t bytes) {
        char* p = w;
        w += (bytes + 15) & ~(size_t)15;
        return p;
    };
    unsigned short* Pt1 = (unsigned short*)carve((size_t)n_nodes * 64 * 2);
    unsigned short* Pt2 = (unsigned short*)carve((size_t)n_nodes * 64 * 2);
    float* q1    = (float*)carve((size_t)n_nodes * 8 * 4);
    float* q2    = (float*)carve((size_t)n_nodes * 8 * 4);
    float* h1pre = (float*)carve((size_t)n_nodes * 8 * 4);
    float* h2pre = (float*)carve((size_t)n_nodes * 8 * 4);
    int* cnt       = (int*)carve((size_t)n_nodes * 4);
    int* excl      = (int*)carve((size_t)n_nodes * 4);
    int* row_start = (int*)carve((size_t)n_nodes * 4);
    int* cursor    = (int*)carve((size_t)n_nodes * 4);
    int* bsum      = (int*)carve((size_t)nb * 4);
    int* bsumx     = (int*)carve((size_t)nb * 4);
    int* src_s     = (int*)carve((size_t)E * 4);
    float* ea_s    = (float*)carve((size_t)E * F_EDGE * 4);

    init_out_kernel<<<(out_size + 255) / 256, 256, 0, stream>>>(out, blast, out_size);

    // CSR build (once; graph shared by both layers)
    zero_int_kernel<<<nb, 256, 0, stream>>>(cnt, n_nodes);
    hist_kernel<<<(E + 255) / 256, 256, 0, stream>>>(ei, cnt, E);
    scan1_kernel<<<nb, 256, 0, stream>>>(cnt, excl, bsum, n_nodes);
    scan2_kernel<<<1, 256, 0, stream>>>(bsum, bsumx, nb);
    scan3_kernel<<<nb, 256, 0, stream>>>(excl, bsumx, row_start, cursor, n_nodes);
    scatter_kernel<<<(E + 255) / 256, 256, 0, stream>>>(ei, ea, cursor, src_s, ea_s, E);

    int pblocks = (n_nodes + 31) / 32;
    int ablocks = (n_nodes + 3) / 4;

    // layer 1
    prep_kernel<16, false><<<pblocks, 256, 0, stream>>>(
        x, We1, be1, root1, b1, Pt1, q1, h1pre, n_nodes);
    agg_csr_kernel<<<ablocks, 256, 0, stream>>>(
        row_start, cnt, src_s, ea_s, Pt1, q1, h1pre, n_nodes);

    // layer 2
    prep_kernel<8, true><<<pblocks, 256, 0, stream>>>(
        h1pre, We2, be2, root2, b2, Pt2, q2, h2pre, n_nodes);
    agg_csr_kernel<<<ablocks, 256, 0, stream>>>(
        row_start, cnt, src_s, ea_s, Pt2, q2, h2pre, n_nodes);

    pool_kernel<<<(n_nodes + 1023) / 1024, 256, 0, stream>>>(
        h2pre, batch, Wlast, out, n_nodes, out_size);
}

// Round 5
// 204.387 us; speedup vs baseline: 1.2877x; 1.2877x over previous
//
#include <hip/hip_runtime.h>

#define F_EDGE 8
#define H 8

__device__ __forceinline__ unsigned short f2bf(float f) {
    unsigned u = __float_as_uint(f);
    unsigned r = u + 0x7fffu + ((u >> 16) & 1u);
    return (unsigned short)(r >> 16);
}
__device__ __forceinline__ float bflo(unsigned u) { return __uint_as_float(u << 16); }
__device__ __forceinline__ float bfhi(unsigned u) { return __uint_as_float(u & 0xffff0000u); }

// out[g] = blast (pool accumulates on top)
__global__ void init_out_kernel(float* __restrict__ out,
                                const float* __restrict__ blast, int n) {
    int g = blockIdx.x * blockDim.x + threadIdx.x;
    if (g < n) out[g] = blast[0];
}

// Per-node factorized precompute:
//   Pt[n][j][k] = sum_i feat[n][i] * We[k][i*H+j]   (bf16)
//   q[n][j]     = sum_i feat[n][i] * be[i*H+j]
//   seed[n][j]  = b[j] + sum_i feat[n][i] * root[i*H+j]
template <int IN, bool RELU>
__global__ __launch_bounds__(256) void prep_kernel(
    const float* __restrict__ feat, const float* __restrict__ We,
    const float* __restrict__ be, const float* __restrict__ root,
    const float* __restrict__ b, unsigned short* __restrict__ Pt,
    float* __restrict__ q, float* __restrict__ seed, int n_nodes) {
    __shared__ float sW[IN * H * 12];
    int tid = threadIdx.x;
    for (int t = tid; t < IN * H * 12; t += 256) {
        int r = t / 12, m = t - r * 12;  // r = i*H + j
        float v = 0.f;
        if (m < 8) v = We[m * (IN * H) + r];
        else if (m == 8) v = be[r];
        else if (m == 9) v = root[r];
        sW[t] = v;
    }
    __syncthreads();

    int n = blockIdx.x * 32 + (tid >> 3);
    if (n >= n_nodes) return;
    int j = tid & 7;

    float f[IN];
    const float4* fv = (const float4*)(feat + (long long)n * IN);
#pragma unroll
    for (int i4 = 0; i4 < IN / 4; ++i4) {
        float4 v = fv[i4];
        f[i4 * 4 + 0] = v.x; f[i4 * 4 + 1] = v.y;
        f[i4 * 4 + 2] = v.z; f[i4 * 4 + 3] = v.w;
    }
    if (RELU) {
#pragma unroll
        for (int i = 0; i < IN; ++i) f[i] = f[i] > 0.f ? f[i] : 0.f;
    }

    float p[8] = {0.f, 0.f, 0.f, 0.f, 0.f, 0.f, 0.f, 0.f};
    float qq = 0.f, hr = 0.f;
#pragma unroll
    for (int i = 0; i < IN; ++i) {
        const float* row = &sW[(i * 8 + j) * 12];
        float4 w0 = *(const float4*)row;
        float4 w1 = *(const float4*)(row + 4);
        float2 br = *(const float2*)(row + 8);
        float fi = f[i];
        p[0] = fmaf(fi, w0.x, p[0]); p[1] = fmaf(fi, w0.y, p[1]);
        p[2] = fmaf(fi, w0.z, p[2]); p[3] = fmaf(fi, w0.w, p[3]);
        p[4] = fmaf(fi, w1.x, p[4]); p[5] = fmaf(fi, w1.y, p[5]);
        p[6] = fmaf(fi, w1.z, p[6]); p[7] = fmaf(fi, w1.w, p[7]);
        qq = fmaf(fi, br.x, qq);
        hr = fmaf(fi, br.y, hr);
    }
    uint4 pw;
    pw.x = (unsigned)f2bf(p[0]) | ((unsigned)f2bf(p[1]) << 16);
    pw.y = (unsigned)f2bf(p[2]) | ((unsigned)f2bf(p[3]) << 16);
    pw.z = (unsigned)f2bf(p[4]) | ((unsigned)f2bf(p[5]) << 16);
    pw.w = (unsigned)f2bf(p[6]) | ((unsigned)f2bf(p[7]) << 16);
    *(uint4*)(Pt + ((long long)n * H + j) * F_EDGE) = pw;
    q[(long long)n * H + j] = qq;
    seed[(long long)n * H + j] = hr + b[j];
}

// Edge kernel with 4 independent edges per thread (4x memory-level
// parallelism against the random Pt/q gather latency).
// Edge streams: stream k covers [k*Q, (k+1)*Q); thread t8 (= gid>>3)
// handles edge k*Q + t8 in each stream -> ei/ea loads stay coalesced.
__global__ __launch_bounds__(256) void edge_fact_kernel(
    const int* __restrict__ ei,             // [2, E]
    const float* __restrict__ ea,           // [E, F_EDGE]
    const unsigned short* __restrict__ Pt,  // [n_nodes, H, F_EDGE] bf16
    const float* __restrict__ q,            // [n_nodes, H]
    float* __restrict__ agg,                // [n_nodes, H]
    int E, int Q) {
    long long gid = (long long)blockIdx.x * blockDim.x + threadIdx.x;
    int t8 = (int)(gid >> 3);
    if (t8 >= Q) return;
    int j = (int)(gid & 7);

    int e[4];
    bool v[4];
#pragma unroll
    for (int k = 0; k < 4; ++k) {
        e[k] = t8 + k * Q;
        v[k] = e[k] < E;
    }

    int src[4], dst[4];
#pragma unroll
    for (int k = 0; k < 4; ++k)
        if (v[k]) {
            src[k] = ei[e[k]];
            dst[k] = ei[E + e[k]];
        }

    float4 a0[4], a1[4];
    uint4 pw[4];
    float m[4];
#pragma unroll
    for (int k = 0; k < 4; ++k)
        if (v[k]) {
            const float4* av = (const float4*)(ea + (size_t)e[k] * F_EDGE);
            a0[k] = av[0];
            a1[k] = av[1];
            pw[k] = *(const uint4*)(Pt + ((size_t)src[k] * H + j) * F_EDGE);
            m[k] = q[(size_t)src[k] * H + j];
        }

#pragma unroll
    for (int k = 0; k < 4; ++k)
        if (v[k]) {
            float mm = m[k];
            mm = fmaf(a0[k].x, bflo(pw[k].x), mm);
            mm = fmaf(a0[k].y, bfhi(pw[k].x), mm);
            mm = fmaf(a0[k].z, bflo(pw[k].y), mm);
            mm = fmaf(a0[k].w, bfhi(pw[k].y), mm);
            mm = fmaf(a1[k].x, bflo(pw[k].z), mm);
            mm = fmaf(a1[k].y, bfhi(pw[k].z), mm);
            mm = fmaf(a1[k].z, bflo(pw[k].w), mm);
            mm = fmaf(a1[k].w, bfhi(pw[k].w), mm);
            unsafeAtomicAdd(&agg[(size_t)dst[k] * H + j], mm);
        }
}

// Pool: per-block LDS bins (batch sorted -> few hot bins), one atomic/bin
__global__ __launch_bounds__(256) void pool_kernel(
    const float* __restrict__ h2pre, const int* __restrict__ batch,
    const float* __restrict__ Wlast, float* __restrict__ out,
    int n_nodes, int n_graphs) {
    __shared__ float bins[512];
    bool use_bins = (n_graphs <= 512);
    if (use_bins) {
        for (int t = threadIdx.x; t < n_graphs; t += 256) bins[t] = 0.f;
        __syncthreads();
    }
    float wl[8];
#pragma unroll
    for (int j = 0; j < 8; ++j) wl[j] = Wlast[j];

    int base = blockIdx.x * 1024;
#pragma unroll
    for (int r = 0; r < 4; ++r) {
        int n = base + r * 256 + threadIdx.x;
        if (n < n_nodes) {
            const float4* hv = (const float4*)(h2pre + (long long)n * H);
            float4 h0 = hv[0], h1 = hv[1];
            float c = 0.f;
            c = fmaf(fmaxf(h0.x, 0.f), wl[0], c);
            c = fmaf(fmaxf(h0.y, 0.f), wl[1], c);
            c = fmaf(fmaxf(h0.z, 0.f), wl[2], c);
            c = fmaf(fmaxf(h0.w, 0.f), wl[3], c);
            c = fmaf(fmaxf(h1.x, 0.f), wl[4], c);
            c = fmaf(fmaxf(h1.y, 0.f), wl[5], c);
            c = fmaf(fmaxf(h1.z, 0.f), wl[6], c);
            c = fmaf(fmaxf(h1.w, 0.f), wl[7], c);
            if (use_bins) atomicAdd(&bins[batch[n]], c);
            else unsafeAtomicAdd(&out[batch[n]], c);
        }
    }
    if (use_bins) {
        __syncthreads();
        for (int t = threadIdx.x; t < n_graphs; t += 256) {
            float v = bins[t];
            if (v != 0.f) unsafeAtomicAdd(&out[t], v);
        }
    }
}

extern "C" void kernel_launch(void* const* d_in, const int* in_sizes, int n_in,
                              void* d_out, int out_size, void* d_ws, size_t ws_size,
                              hipStream_t stream) {
    const float* x     = (const float*)d_in[0];
    const int*   ei    = (const int*)d_in[1];
    const float* ea    = (const float*)d_in[2];
    const int*   batch = (const int*)d_in[3];
    const float* We1   = (const float*)d_in[4];
    const float* be1   = (const float*)d_in[5];
    const float* root1 = (const float*)d_in[6];
    const float* b1    = (const float*)d_in[7];
    const float* We2   = (const float*)d_in[8];
    const float* be2   = (const float*)d_in[9];
    const float* root2 = (const float*)d_in[10];
    const float* b2    = (const float*)d_in[11];
    const float* Wlast = (const float*)d_in[12];
    const float* blast = (const float*)d_in[13];
    float* out = (float*)d_out;

    int n_nodes = in_sizes[0] / 16;
    int E = in_sizes[1] / 2;

    size_t nH = (size_t)n_nodes * H;
    unsigned short* Pt1 = (unsigned short*)d_ws;  // n*64 bf16
    unsigned short* Pt2 = Pt1 + (size_t)n_nodes * H * F_EDGE;
    float* q1    = (float*)(Pt2 + (size_t)n_nodes * H * F_EDGE);
    float* q2    = q1 + nH;
    float* h1pre = q2 + nH;
    float* h2pre = h1pre + nH;

    init_out_kernel<<<(out_size + 255) / 256, 256, 0, stream>>>(out, blast, out_size);

    int nblocks = (n_nodes + 31) / 32;
    prep_kernel<16, false><<<nblocks, 256, 0, stream>>>(
        x, We1, be1, root1, b1, Pt1, q1, h1pre, n_nodes);

    int Q = (E + 3) / 4;
    long long lanes = (long long)Q * H;
    int eblks = (int)((lanes + 255) / 256);
    edge_fact_kernel<<<eblks, 256, 0, stream>>>(ei, ea, Pt1, q1, h1pre, E, Q);

    prep_kernel<8, true><<<nblocks, 256, 0, stream>>>(
        h1pre, We2, be2, root2, b2, Pt2, q2, h2pre, n_nodes);

    edge_fact_kernel<<<eblks, 256, 0, stream>>>(ei, ea, Pt2, q2, h2pre, E, Q);

    pool_kernel<<<(n_nodes + 1023) / 1024, 256, 0, stream>>>(
        h2pre, batch, Wlast, out, n_nodes, out_size);
}